// Round 2
// baseline (168.293 us; speedup 1.0000x reference)
//
#include <hip/hip_runtime.h>

// y = (x + pe) * keep / 0.9 ; pe[s,d] = sin/cos(s * 10000^(-2d/512))
// B=8, S=4096, D=512 -> 16,777,216 fp32 elements, 192 MiB traffic. Memory-bound.
//
// R2: 4 float4s per thread (chunk stride 256 float4s = 2 rows) for MLP;
// exp2 chain hoisted (d invariant across a thread's chunks); nontemporal stores.

static constexpr float KEEP_SCALE = 1.0f / 0.9f;
static constexpr float INV_2PI    = 0.15915494309189535f;
static constexpr float RATIO      = 0.96466155f;           // 10000^(-2/512)
static constexpr float C_LOG2     = -0.05190512648261547f; // -(2/512)*log2(10000)

typedef float vfloat4 __attribute__((ext_vector_type(4)));

__device__ __forceinline__ float sin_rev(float a) {
    float r = a * INV_2PI;
    r -= floorf(r);                       // range-reduce to [0,1) revolutions
    return __builtin_amdgcn_sinf(r);      // v_sin_f32: input in revolutions
}
__device__ __forceinline__ float cos_rev(float a) {
    float r = a * INV_2PI;
    r -= floorf(r);
    return __builtin_amdgcn_cosf(r);
}

static constexpr int VPT = 4;  // float4s per thread

__global__ __launch_bounds__(256) void pe_dropout_kernel(
    const float4* __restrict__ x,
    const float4* __restrict__ m,
    float4* __restrict__ o)
{
    const int base = blockIdx.x * (256 * VPT) + threadIdx.x;

    // Issue all loads before any compute: 8 x 16B in flight per thread.
    float4 xv[VPT], mv[VPT];
#pragma unroll
    for (int i = 0; i < VPT; ++i) xv[i] = x[base + i * 256];
#pragma unroll
    for (int i = 0; i < VPT; ++i) mv[i] = m[base + i * 256];

    // element index e = base*4 + chunk*1024. D=512 -> d = e & 511 is chunk-invariant:
    // d = (threadIdx&127)*4. Row = e>>9 advances by 2 per chunk; a block spans 8 rows
    // aligned to 8, and 8 | 4096, so s = row & 4095 never wraps inside a block.
    const int d = (threadIdx.x & 127) << 2;
    const float s0 = (float)((base >> 7) & 4095);

    float inv0 = exp2f(C_LOG2 * (float)d);
    float inv1 = inv0 * RATIO;
    float inv2 = inv1 * RATIO;
    float inv3 = inv2 * RATIO;

#pragma unroll
    for (int i = 0; i < VPT; ++i) {
        const float s = s0 + 2.0f * (float)i;
        float4 yv;
        yv.x = (xv[i].x + sin_rev(s * inv0)) * (mv[i].x >= 0.1f ? KEEP_SCALE : 0.0f);
        yv.y = (xv[i].y + cos_rev(s * inv1)) * (mv[i].y >= 0.1f ? KEEP_SCALE : 0.0f);
        yv.z = (xv[i].z + sin_rev(s * inv2)) * (mv[i].z >= 0.1f ? KEEP_SCALE : 0.0f);
        yv.w = (xv[i].w + cos_rev(s * inv3)) * (mv[i].w >= 0.1f ? KEEP_SCALE : 0.0f);
        // Output is never re-read: nontemporal store keeps inputs resident in L3.
        __builtin_nontemporal_store(*(const vfloat4*)&yv, (vfloat4*)&o[base + i * 256]);
    }
}

// Tail kernel (unused for the fixed 8x4096x512 shape, kept for robustness).
__global__ __launch_bounds__(256) void pe_dropout_tail(
    const float4* __restrict__ x,
    const float4* __restrict__ m,
    float4* __restrict__ o,
    int start, int total4)
{
    int idx = start + blockIdx.x * 256 + threadIdx.x;
    if (idx >= total4) return;
    int e = idx << 2;
    int d = e & 511;
    float s = (float)((e >> 9) & 4095);
    float inv0 = exp2f(C_LOG2 * (float)d);
    float inv1 = inv0 * RATIO, inv2 = inv1 * RATIO, inv3 = inv2 * RATIO;
    float4 xv = x[idx], mv = m[idx], yv;
    yv.x = (xv.x + sin_rev(s * inv0)) * (mv.x >= 0.1f ? KEEP_SCALE : 0.0f);
    yv.y = (xv.y + cos_rev(s * inv1)) * (mv.y >= 0.1f ? KEEP_SCALE : 0.0f);
    yv.z = (xv.z + sin_rev(s * inv2)) * (mv.z >= 0.1f ? KEEP_SCALE : 0.0f);
    yv.w = (xv.w + cos_rev(s * inv3)) * (mv.w >= 0.1f ? KEEP_SCALE : 0.0f);
    o[idx] = yv;
}

extern "C" void kernel_launch(void* const* d_in, const int* in_sizes, int n_in,
                              void* d_out, int out_size, void* d_ws, size_t ws_size,
                              hipStream_t stream) {
    const float4* x = (const float4*)d_in[0];
    const float4* m = (const float4*)d_in[1];
    float4* out = (float4*)d_out;

    const int n = in_sizes[0];           // 16,777,216
    const int total4 = n >> 2;           // 4,194,304 float4s
    const int per_block = 256 * VPT;     // 1024 float4s per block
    const int full_blocks = total4 / per_block;   // 4096
    const int rem = total4 - full_blocks * per_block;

    if (full_blocks > 0)
        pe_dropout_kernel<<<full_blocks, 256, 0, stream>>>(x, m, out);
    if (rem > 0)
        pe_dropout_tail<<<(rem + 255) / 256, 256, 0, stream>>>(
            x, m, out, full_blocks * per_block, total4);
}

// Round 3
// 167.851 us; speedup vs baseline: 1.0026x; 1.0026x over previous
//
#include <hip/hip_runtime.h>

// y = (x + pe) * keep / 0.9 ; pe[s,d] = sin/cos(s * 10000^(-2d/512))
// B=8, S=4096, D=512 -> 16.7M fp32 elements, 192 MiB kernel traffic.
// R3: falsification round for the harness-drain-bound theory.
// VPT=2, 512-thread blocks, plain stores. Predict 58-62 us (unchanged).

static constexpr float KEEP_SCALE = 1.0f / 0.9f;
static constexpr float INV_2PI    = 0.15915494309189535f;
static constexpr float RATIO      = 0.96466155f;           // 10000^(-2/512)
static constexpr float C_LOG2     = -0.05190512648261547f; // -(2/512)*log2(10000)

__device__ __forceinline__ float sin_rev(float a) {
    float r = a * INV_2PI;
    r -= floorf(r);                       // range-reduce to [0,1) revolutions
    return __builtin_amdgcn_sinf(r);      // v_sin_f32: input in revolutions
}
__device__ __forceinline__ float cos_rev(float a) {
    float r = a * INV_2PI;
    r -= floorf(r);
    return __builtin_amdgcn_cosf(r);
}

static constexpr int BLK = 512;   // threads per block
static constexpr int VPT = 2;     // float4s per thread

__global__ __launch_bounds__(BLK) void pe_dropout_kernel(
    const float4* __restrict__ x,
    const float4* __restrict__ m,
    float4* __restrict__ o)
{
    const int base = blockIdx.x * (BLK * VPT) + threadIdx.x;

    // All 4 loads issued before any compute: 64 B of reads in flight per thread.
    float4 xv[VPT], mv[VPT];
#pragma unroll
    for (int i = 0; i < VPT; ++i) xv[i] = x[base + i * BLK];
#pragma unroll
    for (int i = 0; i < VPT; ++i) mv[i] = m[base + i * BLK];

    // Chunk stride = 512 float4s = 2048 elems = 4 rows; d invariant across chunks.
    const int d = (threadIdx.x & 127) << 2;     // D=512 -> 128 float4s per row
    float inv0 = exp2f(C_LOG2 * (float)d);
    float inv1 = inv0 * RATIO;
    float inv2 = inv1 * RATIO;
    float inv3 = inv2 * RATIO;

#pragma unroll
    for (int i = 0; i < VPT; ++i) {
        const int idx = base + i * BLK;
        const float s = (float)((idx >> 7) & 4095);   // row index, S=4096
        float4 yv;
        yv.x = (xv[i].x + sin_rev(s * inv0)) * (mv[i].x >= 0.1f ? KEEP_SCALE : 0.0f);
        yv.y = (xv[i].y + cos_rev(s * inv1)) * (mv[i].y >= 0.1f ? KEEP_SCALE : 0.0f);
        yv.z = (xv[i].z + sin_rev(s * inv2)) * (mv[i].z >= 0.1f ? KEEP_SCALE : 0.0f);
        yv.w = (xv[i].w + cos_rev(s * inv3)) * (mv[i].w >= 0.1f ? KEEP_SCALE : 0.0f);
        o[idx] = yv;
    }
}

// Tail kernel (unused for the fixed 8x4096x512 shape, kept for robustness).
__global__ __launch_bounds__(256) void pe_dropout_tail(
    const float4* __restrict__ x,
    const float4* __restrict__ m,
    float4* __restrict__ o,
    int start, int total4)
{
    int idx = start + blockIdx.x * 256 + threadIdx.x;
    if (idx >= total4) return;
    int e = idx << 2;
    int d = e & 511;
    float s = (float)((e >> 9) & 4095);
    float inv0 = exp2f(C_LOG2 * (float)d);
    float inv1 = inv0 * RATIO, inv2 = inv1 * RATIO, inv3 = inv2 * RATIO;
    float4 xv = x[idx], mv = m[idx], yv;
    yv.x = (xv.x + sin_rev(s * inv0)) * (mv.x >= 0.1f ? KEEP_SCALE : 0.0f);
    yv.y = (xv.y + cos_rev(s * inv1)) * (mv.y >= 0.1f ? KEEP_SCALE : 0.0f);
    yv.z = (xv.z + sin_rev(s * inv2)) * (mv.z >= 0.1f ? KEEP_SCALE : 0.0f);
    yv.w = (xv.w + cos_rev(s * inv3)) * (mv.w >= 0.1f ? KEEP_SCALE : 0.0f);
    o[idx] = yv;
}

extern "C" void kernel_launch(void* const* d_in, const int* in_sizes, int n_in,
                              void* d_out, int out_size, void* d_ws, size_t ws_size,
                              hipStream_t stream) {
    const float4* x = (const float4*)d_in[0];
    const float4* m = (const float4*)d_in[1];
    float4* out = (float4*)d_out;

    const int n = in_sizes[0];                 // 16,777,216
    const int total4 = n >> 2;                 // 4,194,304 float4s
    const int per_block = BLK * VPT;           // 1024 float4s per block
    const int full_blocks = total4 / per_block;   // 4096
    const int rem = total4 - full_blocks * per_block;

    if (full_blocks > 0)
        pe_dropout_kernel<<<full_blocks, BLK, 0, stream>>>(x, m, out);
    if (rem > 0)
        pe_dropout_tail<<<(rem + 255) / 256, 256, 0, stream>>>(
            x, m, out, full_blocks * per_block, total4);
}